// Round 11
// baseline (508.251 us; speedup 1.0000x reference)
//
#include <hip/hip_runtime.h>
#include <math.h>

constexpr int D = 64;      // input / output feature dim
constexpr int H = 128;     // GRU hidden dim
constexpr int MAXLEN = 512;
constexpr int MSEQ = 4;    // sequences per block (4x N-col duplication)

typedef __attribute__((ext_vector_type(8))) short short8;  // 8 bf16 = 4 VGPRs
typedef __attribute__((ext_vector_type(4))) float f32x4;   // MFMA accumulator

__device__ __forceinline__ short f2bf(float f) {           // f32 -> bf16 RNE (weight packs)
    unsigned u = __float_as_uint(f);
    u += 0x7fffu + ((u >> 16) & 1u);
    return (short)(u >> 16);
}
// HW packed convert: 2 x f32 -> 2 x bf16 (RNE), single VALU instr
__device__ __forceinline__ unsigned cvtpk(float a, float b) {
    unsigned r;
    asm volatile("v_cvt_pk_bf16_f32 %0, %1, %2" : "=v"(r) : "v"(a), "v"(b));
    return r;
}
__device__ __forceinline__ short8 pack8(float4 a, float4 b) {
    short8 r;
    r[0]=f2bf(a.x); r[1]=f2bf(a.y); r[2]=f2bf(a.z); r[3]=f2bf(a.w);
    r[4]=f2bf(b.x); r[5]=f2bf(b.y); r[6]=f2bf(b.z); r[7]=f2bf(b.w);
    return r;
}
__device__ __forceinline__ float rcp_(float x) { return __builtin_amdgcn_rcpf(x); }
__device__ __forceinline__ float sig_(float v) { return rcp_(1.0f + __expf(-v)); }
__device__ __forceinline__ float tanh_(float v) {          // round-6/10 verified form
    float a = fabsf(v);
    float e = __expf(2.0f * a);
    float t = 1.0f - 2.0f * rcp_(e + 1.0f);
    return copysignf(t, v);
}
// lgkm-only barrier: orders LDS producer->consumer without draining vmcnt;
// global x prefetches stay in flight across the barrier (T4 pattern).
__device__ __forceinline__ void lgkm_barrier() {
    asm volatile("s_waitcnt lgkmcnt(0)\n\ts_barrier" ::: "memory");
}
// static 4-way select (cndmask chain; rule-#20-safe, no runtime indexing)
__device__ __forceinline__ float sel4(f32x4 c, bool b0, bool b1) {
    float a = b0 ? c[1] : c[0];
    float b = b0 ? c[3] : c[2];
    return b1 ? b : a;
}

#define MFMA(a,b,c) __builtin_amdgcn_mfma_f32_16x16x32_bf16((a),(b),(c),0,0,0)

// 512 threads = 8 waves. MSEQ=4 -> grid 512 = TWO INDEPENDENT BLOCKS PER CU
// (separate barrier domains de-phase and fill each other's latency bubbles).
// Swapped operands: gates^T[384,16] = W[384,K].state^T[K,16]; N-cols s, s+4,
// s+8, s+12 duplicate seq sq=s&3 -> h ds_reads are 4-way broadcast and each
// lane finishes exactly ONE feature (j2 = s>>2): 6 transcendentals/lane/step.
// A-frag = weight rows (registers). h/x: bf16 XOR-swizzled double-buffered
// LDS; fp32 master h in registers. One lgkm-only barrier per step.
__global__ __launch_bounds__(512, 4)
void gru_m4(const float* __restrict__ x,
            const int* __restrict__ offsets,   // int32 (JAX x64 disabled)
            const float* __restrict__ W_ih,
            const float* __restrict__ W_hh,
            const float* __restrict__ W_dense,
            const float* __restrict__ b_dense,
            float* __restrict__ out,
            int B, int T)
{
    const int bb  = blockIdx.x;
    const int tid = threadIdx.x;      // 0..511
    const int w   = tid >> 6;         // wave 0..7
    const int l   = tid & 63;
    const int s   = l & 15;           // MFMA m/n index
    const int q   = l >> 4;           // k-group 0..3
    const int sq  = s & 3;            // sequence within block (4x dup)
    const int j2  = s >> 2;           // 0..3: which C row (feature) this lane owns
    const bool jb0 = (j2 & 1) != 0, jb1 = (j2 & 2) != 0;

    __shared__ __align__(16) short h_bf[2][MSEQ * H];   // 2 x 1KB, row 256B, XOR-swizzled
    __shared__ __align__(16) short x_bf[2][MSEQ * D];   // 2 x 512B, row 128B, XOR-swizzled
    __shared__ int slen[MSEQ], sstart[MSEQ];
    __shared__ float h_f32[MSEQ][H];

    // ---- sequence bounds ----
    if (tid < MSEQ) {
        int sg = bb * MSEQ + tid;
        int st = 0, en = 1;
        if (sg < B) { st = offsets[sg]; en = (sg + 1 < B) ? offsets[sg + 1] : T; }
        int ln = en - st;
        ln = max(1, min(ln, MAXLEN));
        sstart[tid] = st; slen[tid] = ln;
    }
    if (tid < 256) ((int*)h_bf[0])[tid] = 0;   // zero h buffer 0 (256 dwords)
    __syncthreads();

    int nt = 1;
#pragma unroll
    for (int i = 0; i < MSEQ; ++i) nt = max(nt, slen[i]);

    // ---- A-frags: weight rows in registers (one-time). Row = g*H + w*16 + s ----
    short8 Wh[3][4];   // [gate][kt], K=128
    short8 Wi[3][2];   // [gate][kt], K=64
#pragma unroll
    for (int g = 0; g < 3; ++g) {
        const int grow = g * H + w * 16 + s;
        const float* ph = W_hh + (size_t)grow * H + q * 8;
#pragma unroll
        for (int kt = 0; kt < 4; ++kt)
            Wh[g][kt] = pack8(*(const float4*)(ph + kt * 32),
                              *(const float4*)(ph + kt * 32 + 4));
        const float* pi = W_ih + (size_t)grow * D + q * 8;
#pragma unroll
        for (int kt = 0; kt < 2; ++kt)
            Wi[g][kt] = pack8(*(const float4*)(pi + kt * 32),
                              *(const float4*)(pi + kt * 32 + 4));
    }

    // ---- per-lane LDS byte offsets (16B-chunk XOR swizzle keyed by row sq) ----
    int hoff[4], xoff[2];
#pragma unroll
    for (int kt = 0; kt < 4; ++kt) hoff[kt] = sq * 256 + (((kt * 4 + q) ^ sq) << 4);
#pragma unroll
    for (int kt = 0; kt < 2; ++kt) xoff[kt] = sq * 128 + (((kt * 4 + q) ^ sq) << 4);
    // h write: ONE bf16 at feature f0 = w*16 + q*4 + j2, row sq.
    // chunk = 2w + (q>>1); byte-in-chunk = (q&1)*8 + j2*2
    const int woff = sq * 256 + ((((2 * w) + (q >> 1)) ^ sq) << 4)
                   + ((q & 1) << 3) + (j2 << 1);

    // ---- x staging: row = w&3, halves split by w>>2; lanes l<16 (balanced) ----
    const bool xact = (l < 16);
    const int  xrow = w & 3;
    const int  pxx  = ((w >> 2) << 4) + l;      // float2 index 0..31 within row
    const int  st_x = sstart[xrow];
    const int  ln_x = slen[xrow];
    const float* xg = x + (size_t)st_x * D + pxx * 2;
    const int xwoff = xrow * 128 + (((pxx >> 2) ^ xrow) << 4) + ((pxx & 3) << 2);

    if (xact) {   // stage x row 0 into buf 0
        float2 v = *(const float2*)xg;
        *(unsigned*)((char*)x_bf[0] + xwoff) = cvtpk(v.x, v.y);
    }
    float2 xpf = {0.f, 0.f};
    if (xact) xpf = *(const float2*)(xg + (size_t)min(1, ln_x - 1) * D);

    const int ln_s = slen[sq];
    float h0 = 0.f;                   // fp32 master state: ONE feature/lane

    __syncthreads();                  // x_bf[0], h_bf[0] visible

    for (int t = 0; t < nt; ++t) {
        const int p = t & 1;
        const char* hb = (const char*)h_bf[p];
        const char* xb = (const char*)x_bf[p];

        short8 bh[4], bx[2];
#pragma unroll
        for (int kt = 0; kt < 4; ++kt) bh[kt] = *(const short8*)(hb + hoff[kt]);
#pragma unroll
        for (int kt = 0; kt < 2; ++kt) bx[kt] = *(const short8*)(xb + xoff[kt]);

        // issue x(t+2) prefetch (consumed next step's staging; never drained)
        float2 xnew = {0.f, 0.f};
        if (xact) {
            const int tn = (t + 2 < ln_x) ? t + 2 : ln_x - 1;
            xnew = *(const float2*)(xg + (size_t)tn * D);
        }

        // 18 MFMAs: gates^T = W . state^T  (4 independent chains)
        __builtin_amdgcn_s_setprio(1);
        f32x4 cr = {0,0,0,0}, cz = {0,0,0,0}, ci = {0,0,0,0}, chh = {0,0,0,0};
#pragma unroll
        for (int kt = 0; kt < 2; ++kt) {
            cr = MFMA(Wi[0][kt], bx[kt], cr);
            cz = MFMA(Wi[1][kt], bx[kt], cz);
            ci = MFMA(Wi[2][kt], bx[kt], ci);
        }
#pragma unroll
        for (int kt = 0; kt < 4; ++kt) {
            cr  = MFMA(Wh[0][kt], bh[kt], cr);
            cz  = MFMA(Wh[1][kt], bh[kt], cz);
            chh = MFMA(Wh[2][kt], bh[kt], chh);
        }
        __builtin_amdgcn_s_setprio(0);

        // gate math on this lane's ONE feature (static cndmask select)
        {
            float vr = sel4(cr, jb0, jb1);
            float vz = sel4(cz, jb0, jb1);
            float vi = sel4(ci, jb0, jb1);
            float vh = sel4(chh, jb0, jb1);
            float r  = sig_(vr);
            float z  = sig_(vz);
            float n  = tanh_(vi + r * vh);
            float hn = (1.0f - z) * n + z * h0;
            h0 = (t < ln_s) ? hn : h0;
        }

        // publish h' (one b16) + stage x(t+1) into buffer p^1
        {
            unsigned hu = cvtpk(h0, h0);
            *(short*)((char*)h_bf[p ^ 1] + woff) = (short)hu;
        }
        if (xact)
            *(unsigned*)((char*)x_bf[p ^ 1] + xwoff) = cvtpk(xpf.x, xpf.y);
        xpf = xnew;       // rotate prefetch register

        lgkm_barrier();   // LDS-only drain; x prefetch stays in flight
    }

    // ---- epilogue: h -> LDS fp32 (lane owns one feature) ----
    h_f32[sq][w * 16 + q * 4 + j2] = h0;
    __syncthreads();

    // dense(128->64) + L2 normalize: 4 seqs x 64 cols = threads 0..255
    if (tid < 256) {
        const int s2 = tid >> 6;      // seq 0..3
        const int cb = tid & 63;      // col 0..63
        float acc = b_dense[cb];
        const float* wd = W_dense + (size_t)cb * H;
        float a0=0.f,a1=0.f,a2=0.f,a3=0.f;
#pragma unroll
        for (int j = 0; j < H; j += 4) {
            float4 hv = *(const float4*)&h_f32[s2][j];   // wave-uniform broadcast
            float4 wv = *(const float4*)(wd + j);
            a0 += hv.x*wv.x; a1 += hv.y*wv.y; a2 += hv.z*wv.z; a3 += hv.w*wv.w;
        }
        acc += (a0 + a1) + (a2 + a3);
        float s2q = acc * acc;
#pragma unroll
        for (int off = 32; off >= 1; off >>= 1) s2q += __shfl_xor(s2q, off);
        float invn = 1.0f / fmaxf(sqrtf(s2q), 1e-12f);
        int sg = bb * MSEQ + s2;
        if (sg < B) out[(size_t)sg * D + cb] = acc * invn;
    }
}

extern "C" void kernel_launch(void* const* d_in, const int* in_sizes, int n_in,
                              void* d_out, int out_size, void* d_ws, size_t ws_size,
                              hipStream_t stream) {
    const float* x       = (const float*)d_in[0];
    const int*   offsets = (const int*)d_in[1];
    const float* W_ih    = (const float*)d_in[2];
    const float* W_hh    = (const float*)d_in[3];
    const float* W_dense = (const float*)d_in[4];
    const float* b_dense = (const float*)d_in[5];
    float*       out     = (float*)d_out;

    const int B = in_sizes[1];
    const int T = in_sizes[0] / D;
    const int grid = (B + MSEQ - 1) / MSEQ;

    gru_m4<<<grid, 512, 0, stream>>>(x, offsets, W_ih, W_hh, W_dense, b_dense, out, B, T);
}